// Round 7
// baseline (783.517 us; speedup 1.0000x reference)
//
#include <hip/hip_runtime.h>
#include <math.h>

// Problem constants
constexpr int NB = 32, ND = 512, NHID = 512, NSTEPS = 31;
constexpr int NC5 = 2560;          // 5H
constexpr int BH = NB * NHID;      // 16384
constexpr int SLOT_Z = 32;         // zero h/c slot
constexpr int SLOT_DUMMY = 126;    // dummy candidate (never read)
constexpr int NSLOTS = 128;        // 0..31 leaves, 32 zero, 33..63 step0 cands,
                                   // 64+2s/65+2s cands of step s+1, 126 dummy
constexpr int NBLK = 128;          // unit blocks (4 hidden units each); 0..31 dual owner

constexpr float INV2048 = 1.f / 2048.f;

typedef _Float16 half8  __attribute__((ext_vector_type(8)));
typedef _Float16 half4  __attribute__((ext_vector_type(4)));
typedef float    f32x16 __attribute__((ext_vector_type(16)));
typedef unsigned long long u64;

// ---------------- workspace layout (float offsets) ----------------
constexpr size_t OFF_WTH  = 0;                                   // W^T hi [2560][1024] halves
constexpr size_t OFF_WTL  = OFF_WTH + (size_t)NC5 * 1024 / 2;
constexpr size_t OFF_WPH  = OFF_WTL + (size_t)NC5 * 1024 / 2;    // permuted [128][32][1024] halves
constexpr size_t OFF_WPL  = OFF_WPH + (size_t)128 * 32 * 1024 / 2;
constexpr size_t OFF_HHI  = OFF_WPL + (size_t)128 * 32 * 1024 / 2; // [128][32][512] halves
constexpr size_t OFF_HLO  = OFF_HHI + (size_t)NSLOTS * 32 * 512 / 2;
constexpr size_t OFF_HF32 = OFF_HLO + (size_t)NSLOTS * 32 * 512 / 2; // [128][32][512] f32
constexpr size_t OFF_CST  = OFF_HF32 + (size_t)NSLOTS * 32 * 512;  // leaf c [32][32][512]
constexpr size_t OFF_CLOC = OFF_CST + (size_t)32 * 32 * 512;     // [128blk][128][32][4] f32
constexpr size_t OFF_LPART= OFF_CLOC + (size_t)128 * NSLOTS * 32 * 4; // [128][32][128] f32
constexpr size_t OFF_SEL  = OFF_LPART + (size_t)NSLOTS * 32 * 128;  // int [31][32]
constexpr size_t OFF_ELIST= OFF_SEL + 1024;                      // u64 [31][64]
constexpr size_t OFF_IREG = OFF_ELIST + 4096;                    // ints: gd[128] + E0[992]

constexpr int IR_GD = 0;
constexpr int IR_E0 = 256;

__device__ __forceinline__ float sigf(float x) { return 1.f / (1.f + expf(-x)); }

// device-scope (L2-bypassing) helpers
__device__ __forceinline__ int ld_sc(const int* p) {
    return __hip_atomic_load(p, __ATOMIC_RELAXED, __HIP_MEMORY_SCOPE_AGENT);
}
__device__ __forceinline__ u64 ld_sc64(const void* p) {
    return __hip_atomic_load((const u64*)p, __ATOMIC_RELAXED, __HIP_MEMORY_SCOPE_AGENT);
}
__device__ __forceinline__ void st_sc64(void* p, u64 v) {
    __hip_atomic_store((u64*)p, v, __ATOMIC_RELAXED, __HIP_MEMORY_SCOPE_AGENT);
}
__device__ __forceinline__ void st_sc32f(void* p, float v) {
    __hip_atomic_store((int*)p, __float_as_int(v), __ATOMIC_RELAXED, __HIP_MEMORY_SCOPE_AGENT);
}
__device__ __forceinline__ void st_sc32i(void* p, int v) {
    __hip_atomic_store((int*)p, v, __ATOMIC_RELAXED, __HIP_MEMORY_SCOPE_AGENT);
}
// entry pack: b[0:5) cand[5:12) l[12:19) r[19:26)
__device__ __forceinline__ unsigned pack_e(int b, int cand, int l, int r) {
    return (unsigned)b | ((unsigned)cand << 5) | ((unsigned)l << 12) | ((unsigned)r << 19);
}

// ---------------- init: E0 list, counters, elist, zero h slot ----------------
__global__ __launch_bounds__(256) void init_kernel(
    int* __restrict__ ireg, u64* __restrict__ elist,
    _Float16* __restrict__ hHi, _Float16* __restrict__ hLo)
{
    const int blk = blockIdx.x, tid = threadIdx.x;
    if (blk == 0) {
        for (int i = tid; i < 128; i += 256) ireg[IR_GD + i] = 0;
        for (int i = tid; i < 992; i += 256) {
            int t = i >> 5, b = i & 31;
            ireg[IR_E0 + i] = (int)pack_e(b, 33 + t, t, t + 1);
        }
    } else if (blk == 1) {
        for (int i = tid; i < 31 * 64; i += 256) elist[i] = 0ull;
    } else {
        // zero h slot 32
        const size_t zb = ((size_t)SLOT_Z * 32) * 512;
        for (int i = tid + (blk - 2) * 256; i < 32 * 512; i += 512) {
            hHi[zb + i] = (_Float16)0.f;
            hLo[zb + i] = (_Float16)0.f;
        }
    }
}

// ---------------- W_comp -> transposed split fp16 planes ----------------
__global__ __launch_bounds__(256) void wsplit_kernel(
    const float* __restrict__ W, _Float16* __restrict__ Wth, _Float16* __restrict__ Wtl)
{
    __shared__ float t[32][33];
    const int n0 = blockIdx.x * 32, k0 = blockIdx.y * 32;
    const int tid = threadIdx.x;
    const int c = tid & 31, r8 = tid >> 5;
#pragma unroll
    for (int p = 0; p < 4; ++p) {
        int r = p * 8 + r8;
        t[r][c] = W[(size_t)(k0 + r) * NC5 + n0 + c];
    }
    __syncthreads();
    const int nl = tid >> 3, k4 = (tid & 7) * 4;
    half4 vh, vl;
#pragma unroll
    for (int i = 0; i < 4; ++i) {
        float v = t[k4 + i][nl];
        _Float16 hh = (_Float16)v;
        vh[i] = hh;
        vl[i] = (_Float16)((v - (float)hh) * 2048.f);
    }
    size_t o = (size_t)(n0 + nl) * 1024 + k0 + k4;
    *(half4*)&Wth[o] = vh;
    *(half4*)&Wtl[o] = vl;
}

// ---------------- permute W^T into per-block unit-gate panels ----------------
// Block blk owns hidden units blk*4..+3; col c<20: unit=blk*4+c/5, gate=c%5,
// source row n = gate*512+unit. Cols 20..31 zero.
__global__ __launch_bounds__(256) void wperm_kernel(
    const _Float16* __restrict__ Wth, const _Float16* __restrict__ Wtl,
    _Float16* __restrict__ WpH, _Float16* __restrict__ WpL)
{
    const int blk = blockIdx.x;
    const int tid = threadIdx.x;
    const int k4 = tid * 4;                 // 0..1020
    for (int c = 0; c < 32; ++c) {
        half4 vh = (half4)(_Float16)0.f, vl = (half4)(_Float16)0.f;
        if (c < 20) {
            int unit = blk * 4 + c / 5, g = c % 5;
            size_t src = (size_t)(g * 512 + unit) * 1024 + k4;
            vh = *(const half4*)&Wth[src];
            vl = *(const half4*)&Wtl[src];
        }
        size_t dst = ((size_t)blk * 32 + c) * 1024 + k4;
        *(half4*)&WpH[dst] = vh;
        *(half4*)&WpL[dst] = vl;
    }
}

// ---------------- word GEMM: leaves -> h slots 0..31, leaf c, nodes ----------------
__global__ __launch_bounds__(256) void word_gemm64(
    const float* __restrict__ A, const float* __restrict__ W,
    const float* __restrict__ bias,
    _Float16* __restrict__ hi0, _Float16* __restrict__ lo0,
    float* __restrict__ cst, float* __restrict__ out)
{
    const int m0 = blockIdx.x * 64;
    const int n0 = blockIdx.y * 64;
    const int tid = threadIdx.x;
    const int tx = tid & 15, ty = tid >> 4;
    __shared__ float As[16][64];
    __shared__ float Bs[16][64];
    float acc[4][4];
#pragma unroll
    for (int i = 0; i < 4; ++i)
#pragma unroll
        for (int j = 0; j < 4; ++j) acc[i][j] = 0.f;

    for (int kt = 0; kt < ND; kt += 16) {
        {
            int row = tid >> 2, kq = tid & 3;
            float4 v = *(const float4*)(A + (size_t)(m0 + row) * ND + kt + kq * 4);
            As[kq * 4 + 0][row] = v.x;
            As[kq * 4 + 1][row] = v.y;
            As[kq * 4 + 2][row] = v.z;
            As[kq * 4 + 3][row] = v.w;
            int kr = tid >> 4, nq = tid & 15;
            float4 vb = *(const float4*)(W + (size_t)(kt + kr) * 1024 + n0 + nq * 4);
            *(float4*)&Bs[kr][nq * 4] = vb;
        }
        __syncthreads();
#pragma unroll
        for (int kk = 0; kk < 16; ++kk) {
            float a0 = As[kk][ty * 4 + 0], a1 = As[kk][ty * 4 + 1];
            float a2 = As[kk][ty * 4 + 2], a3 = As[kk][ty * 4 + 3];
            float4 bv = *(float4*)&Bs[kk][tx * 4];
            acc[0][0] = fmaf(a0, bv.x, acc[0][0]); acc[0][1] = fmaf(a0, bv.y, acc[0][1]);
            acc[0][2] = fmaf(a0, bv.z, acc[0][2]); acc[0][3] = fmaf(a0, bv.w, acc[0][3]);
            acc[1][0] = fmaf(a1, bv.x, acc[1][0]); acc[1][1] = fmaf(a1, bv.y, acc[1][1]);
            acc[1][2] = fmaf(a1, bv.z, acc[1][2]); acc[1][3] = fmaf(a1, bv.w, acc[1][3]);
            acc[2][0] = fmaf(a2, bv.x, acc[2][0]); acc[2][1] = fmaf(a2, bv.y, acc[2][1]);
            acc[2][2] = fmaf(a2, bv.z, acc[2][2]); acc[2][3] = fmaf(a2, bv.w, acc[2][3]);
            acc[3][0] = fmaf(a3, bv.x, acc[3][0]); acc[3][1] = fmaf(a3, bv.y, acc[3][1]);
            acc[3][2] = fmaf(a3, bv.z, acc[3][2]); acc[3][3] = fmaf(a3, bv.w, acc[3][3]);
        }
        __syncthreads();
    }
    float* nodes = out + 2 * BH;
#pragma unroll
    for (int i = 0; i < 4; ++i) {
        int r = m0 + ty * 4 + i;
        int b = r >> 5, l = r & 31;
#pragma unroll
        for (int jn = 0; jn < 4; ++jn) {
            int n = n0 + tx * 4 + jn;
            float v = acc[i][jn] + bias[n];
            if (n < NHID) {
                size_t si = ((size_t)l * NB + b) * NHID + n;
                _Float16 hh = (_Float16)v;
                hi0[si] = hh;
                lo0[si] = (_Float16)((v - (float)hh) * 2048.f);
                nodes[((size_t)b * 63 + l) * NHID + n] = v;
            } else {
                cst[((size_t)l * NB + b) * NHID + (n - NHID)] = v;
            }
        }
    }
}

// ---------------- persistent kernel: fused GEMM+activation per unit-block ----------------
// 128 blocks; block blk owns hidden units blk*4..+3 (20 gate cols in VGPR B panel,
// 12 zero). Per step: MFMA over the 64 fresh pair rows -> gates -> c,h for its
// units (c block-private; h candidate slices sc-published + logit partial).
// Owners (blocks 0..31) then argmax from 128 partials and publish self-stamped
// entries. No graw, no h-materialization wait.
__global__ __launch_bounds__(256, 1) void tree_loop(
    _Float16* __restrict__ hHi, _Float16* __restrict__ hLo, float* __restrict__ hF32,
    const _Float16* __restrict__ WpH, const _Float16* __restrict__ WpL,
    const float* __restrict__ bias, const float* __restrict__ q,
    const int* __restrict__ len, const float* __restrict__ cst,
    float* __restrict__ cLoc, float* __restrict__ lpart,
    u64* __restrict__ elist, int* __restrict__ selLog, int* __restrict__ ireg)
{
    const int blk = blockIdx.x;
    const int tid = threadIdx.x;
    const int kw = tid >> 6, lane = tid & 63;
    const int l5 = lane >> 5, ln = lane & 31;

    int* gd = ireg + IR_GD;
    const int* E0 = ireg + IR_E0;

    __shared__ float red[4][32][32];       // 16 KB
    __shared__ unsigned s_entry[64];
    __shared__ float sH[32][4];
    __shared__ float sLP[32];
    __shared__ float sBias[4][5];
    __shared__ float sQ[4];
    __shared__ float s_plog[128];
    __shared__ int s_pidx[32], s_hidx[32];
    __shared__ int s_k, s_prevk;

    // B panel preload (once): 32 cols x 256 K per wave, hi+lo -> 128 VGPRs.
    const _Float16* bHiP = WpH + ((size_t)blk * 32 + ln) * 1024 + (kw << 8) + l5 * 8;
    const _Float16* bLoP = WpL + ((size_t)blk * 32 + ln) * 1024 + (kw << 8) + l5 * 8;
    half8 Bh[16], Bl[16];
#pragma unroll
    for (int ks = 0; ks < 16; ++ks) {
        Bh[ks] = *(const half8*)(bHiP + ks * 16);
        Bl[ks] = *(const half8*)(bLoP + ks * 16);
    }

    // bias/q slices
    if (tid < 20) { int ul = tid / 5, g = tid % 5; sBias[ul][g] = bias[g * 512 + blk * 4 + ul]; }
    if (tid >= 32 && tid < 36) sQ[tid - 32] = q[blk * 4 + (tid - 32)];

    // block-private c slice: preload leaves (0..31) + zero slot (32)
    float* cB = cLoc + (size_t)blk * NSLOTS * 32 * 4;
    for (int i = tid; i < 33 * 32 * 4; i += 256) {
        int slot = i >> 7, rem = i & 127;
        int b = rem >> 2, ul = rem & 3;
        cB[i] = (slot == SLOT_Z) ? 0.f
                                 : cst[((size_t)slot * 32 + b) * 512 + blk * 4 + ul];
    }

    // owner bookkeeping
    int lenb = 0;
    if (blk < NB) {
        if (tid < 31) s_pidx[tid] = 33 + tid;
        if (tid < 32) s_hidx[tid] = tid;
        if (tid == 0) s_prevk = 0;
        lenb = len[blk];
    }
    __syncthreads();

    for (int step = 0; step < NSTEPS; ++step) {
        int ntiles;
        if (step == 0) {
            ntiles = 31;
        } else {
            ntiles = 2;
            if (tid < 64) {
                u64 e;
                while ((int)((e = ld_sc64(&elist[step * 64 + tid])) >> 32) < step)
                    __builtin_amdgcn_s_sleep(4);
                s_entry[tid] = (unsigned)e;
            }
            __syncthreads();
        }

        for (int t = 0; t < ntiles; ++t) {
            if (step == 0) {
                if (tid < 32) s_entry[tid] = (unsigned)E0[t * 32 + tid];
                __syncthreads();
            }
            const unsigned* se = (step == 0) ? s_entry : s_entry + t * 32;
            // ---- MFMA: 32 pair rows x 32 cols (20 real) ----
            {
                const unsigned e = se[ln];
                const int eb = e & 31;
                const int lsl = (e >> 12) & 127, rsl = (e >> 19) & 127;
                const int hs = (kw < 2) ? lsl : rsl;
                const int koff = ((kw & 1) << 8) + l5 * 8;
                const _Float16* aHiP = hHi + ((size_t)hs * 32 + eb) * 512 + koff;
                const _Float16* aLoP = hLo + ((size_t)hs * 32 + eb) * 512 + koff;
                f32x16 acc1 = (f32x16)0.f, acc2 = (f32x16)0.f;
#pragma unroll
                for (int ks = 0; ks < 16; ++ks) {
                    half8 Ah = *(const half8*)(aHiP + ks * 16);
                    half8 Al = *(const half8*)(aLoP + ks * 16);
                    acc1 = __builtin_amdgcn_mfma_f32_32x32x16_f16(Ah, Bh[ks], acc1, 0, 0, 0);
                    acc2 = __builtin_amdgcn_mfma_f32_32x32x16_f16(Ah, Bl[ks], acc2, 0, 0, 0);
                    acc2 = __builtin_amdgcn_mfma_f32_32x32x16_f16(Al, Bh[ks], acc2, 0, 0, 0);
                }
                // C/D: col=lane&31, row=(a&3)+8*(a>>2)+4*(lane>>5)
#pragma unroll
                for (int a = 0; a < 16; ++a) {
                    int row = (a & 3) + 8 * (a >> 2) + 4 * l5;
                    red[kw][row][ln] = acc1[a] + acc2[a] * INV2048;
                }
            }
            __syncthreads();
            // ---- activation: thread (row r, unit ul) ----
            if (tid < 128) {
                const int r = tid >> 2, ul = tid & 3;
                const unsigned e = se[r];
                const int eb = e & 31, cand = (e >> 5) & 127;
                const int lsl = (e >> 12) & 127, rsl = (e >> 19) & 127;
                const int c0 = ul * 5;
                float g0 = (red[0][r][c0+0] + red[1][r][c0+0]) + (red[2][r][c0+0] + red[3][r][c0+0]);
                float g1 = (red[0][r][c0+1] + red[1][r][c0+1]) + (red[2][r][c0+1] + red[3][r][c0+1]);
                float g2 = (red[0][r][c0+2] + red[1][r][c0+2]) + (red[2][r][c0+2] + red[3][r][c0+2]);
                float g3 = (red[0][r][c0+3] + red[1][r][c0+3]) + (red[2][r][c0+3] + red[3][r][c0+3]);
                float g4 = (red[0][r][c0+4] + red[1][r][c0+4]) + (red[2][r][c0+4] + red[3][r][c0+4]);
                float ig = g0 + sBias[ul][0];
                float fl = g1 + sBias[ul][1];
                float fr = g2 + sBias[ul][2];
                float uu = g3 + sBias[ul][3];
                float oo = g4 + sBias[ul][4];
                float cl = cB[lsl * 128 + eb * 4 + ul];
                float cr = cB[rsl * 128 + eb * 4 + ul];
                float c = cl * sigf(fl + 1.f) + cr * sigf(fr + 1.f) + tanhf(uu) * sigf(ig);
                float h = sigf(oo) * tanhf(c);
                cB[cand * 128 + eb * 4 + ul] = c;      // block-private, plain cached
                sH[r][ul] = h;
                float p = h * sQ[ul];
                p += __shfl_down(p, 1);
                p += __shfl_down(p, 2);
                if (ul == 0) sLP[r] = p;
            }
            __syncthreads();
            // ---- publish h candidate slices + logit partial ----
            if (tid < 32) {
                const unsigned e = se[tid];
                const int eb = e & 31, cand = (e >> 5) & 127;
                float x0 = sH[tid][0], x1 = sH[tid][1], x2 = sH[tid][2], x3 = sH[tid][3];
                half4 hv, lv;
                {
                    _Float16 h0 = (_Float16)x0, h1 = (_Float16)x1,
                             h2 = (_Float16)x2, h3 = (_Float16)x3;
                    hv[0] = h0; hv[1] = h1; hv[2] = h2; hv[3] = h3;
                    lv[0] = (_Float16)((x0 - (float)h0) * 2048.f);
                    lv[1] = (_Float16)((x1 - (float)h1) * 2048.f);
                    lv[2] = (_Float16)((x2 - (float)h2) * 2048.f);
                    lv[3] = (_Float16)((x3 - (float)h3) * 2048.f);
                }
                const size_t so = ((size_t)cand * 32 + eb) * 512 + blk * 4;
                st_sc64(&hHi[so], __builtin_bit_cast(u64, hv));
                st_sc64(&hLo[so], __builtin_bit_cast(u64, lv));
                u64 f01 = (u64)__float_as_uint(x0) | ((u64)__float_as_uint(x1) << 32);
                u64 f23 = (u64)__float_as_uint(x2) | ((u64)__float_as_uint(x3) << 32);
                st_sc64(&hF32[so], f01);
                st_sc64(&hF32[so + 2], f23);
                st_sc32f(&lpart[((size_t)cand * 32 + eb) * 128 + blk], sLP[tid]);
            }
            __syncthreads();
        }
        // drain (syncthreads above waited vmcnt per wave) + arrival bump
        if (tid == 0) {
            asm volatile("s_waitcnt vmcnt(0)" ::: "memory");
            __hip_atomic_fetch_add(&gd[(blk & 3) * 32], 1, __ATOMIC_RELAXED,
                                   __HIP_MEMORY_SCOPE_AGENT);
        }

        // ---- OWNER phase (blocks 0..31) ----
        if (blk < NB) {
            const int b = blk;
            if (tid < 4) {
                const int tgt = 32 * (step + 1);
                while (ld_sc(&gd[tid * 32]) < tgt) __builtin_amdgcn_s_sleep(2);
            }
            __syncthreads();
            // fresh logits: sum 128 block partials (fixed order)
            if (step == 0) {
                if (tid < 64) {
                    for (int j = 0; j < 31; ++j) {
                        const int cand = 33 + j;
                        const float* pp = lpart + ((size_t)cand * 32 + b) * 128;
                        float v = pp[tid] + pp[tid + 64];
#pragma unroll
                        for (int off = 32; off > 0; off >>= 1) v += __shfl_down(v, off);
                        if (tid == 0) s_plog[cand] = v;
                    }
                }
            } else {
                const int pk = s_prevk;
                const int nf = (pk < 0) ? 0 : ((pk >= 1) ? 2 : 1);
                if (tid < 64) {
                    for (int f = 0; f < nf; ++f) {
                        const int pos = pk - (nf - 1) + f;
                        const int cand = s_pidx[pos];
                        const float* pp = lpart + ((size_t)cand * 32 + b) * 128;
                        float v = pp[tid] + pp[tid + 64];
#pragma unroll
                        for (int off = 32; off > 0; off >>= 1) v += __shfl_down(v, off);
                        if (tid == 0) s_plog[cand] = v;
                    }
                }
            }
            __syncthreads();

            // argmax over alive pairs (first-index tie-break)
            const int actb = lenb - 1 - step;
            const int merge = actb >= 1;
            if (tid < 64) {
                float v = -1e30f;
                int idx = tid;
                if (tid < actb && tid < 31) v = s_plog[s_pidx[tid]];
#pragma unroll
                for (int off = 32; off > 0; off >>= 1) {
                    float ov = __shfl_down(v, off);
                    int   oi = __shfl_down(idx, off);
                    if (ov > v || (ov == v && oi < idx)) { v = ov; idx = oi; }
                }
                if (tid == 0) s_k = idx;
            }
            __syncthreads();
            const int k = s_k;
            const int last = (step == NSTEPS - 1);

            if (tid == 0) {
                if (merge) {
                    const int winner = s_pidx[k];
                    const int candA = 64 + 2 * step, candB = 65 + 2 * step;
                    if (!last) {
                        const u64 st = (u64)(step + 1) << 32;
                        unsigned e0 = (k >= 1)
                            ? pack_e(b, candA, s_hidx[k - 1], winner)
                            : pack_e(b, SLOT_DUMMY, SLOT_Z, SLOT_Z);
                        unsigned e1 = pack_e(b, candB, winner,
                                             (k + 2 <= 31) ? s_hidx[k + 2] : SLOT_Z);
                        st_sc64(&elist[(step + 1) * 64 + 2 * b],     (u64)e0 | st);
                        st_sc64(&elist[(step + 1) * 64 + 2 * b + 1], (u64)e1 | st);
                    }
                    st_sc32i(&selLog[step * 32 + b], winner);
                    if (k >= 1) s_pidx[k - 1] = candA;
                    s_pidx[k] = candB;
                    s_hidx[k] = winner;
                    for (int j = k + 1; j <= 30; ++j) s_hidx[j] = s_hidx[j + 1];
                    s_hidx[31] = SLOT_Z;
                    for (int j = k + 1; j <= 29; ++j) s_pidx[j] = s_pidx[j + 1];
                    s_prevk = k;
                } else {
                    if (!last) {
                        const u64 st = (u64)(step + 1) << 32;
                        const unsigned d = pack_e(b, SLOT_DUMMY, SLOT_Z, SLOT_Z);
                        st_sc64(&elist[(step + 1) * 64 + 2 * b],     (u64)d | st);
                        st_sc64(&elist[(step + 1) * 64 + 2 * b + 1], (u64)d | st);
                    }
                    st_sc32i(&selLog[step * 32 + b], last ? s_hidx[0] : s_pidx[0]);
                    s_prevk = -1;
                }
            }
            __syncthreads();
        }
    }
}

// ---------------- gather: nodes rows, hf, cf (off critical path) ----------------
__global__ __launch_bounds__(256) void gather_kernel(
    const float* __restrict__ hF32, const float* __restrict__ cst,
    const float* __restrict__ cLoc, const int* __restrict__ selLog,
    float* __restrict__ out)
{
    const int b = blockIdx.x;
    const int tid = threadIdx.x;
    float* nodes = out + 2 * BH;
    for (int s = 0; s < NSTEPS; ++s) {
        const int id = selLog[s * 32 + b];
        float* dst = nodes + ((size_t)b * 63 + 32 + s) * 512;
        const float* src = (id < 32) ? nodes + ((size_t)b * 63 + id) * 512
                                     : hF32 + ((size_t)id * 32 + b) * 512;
        for (int u = tid; u < 512; u += 256) dst[u] = src[u];
    }
    const int rid = selLog[30 * 32 + b];
    const float* hsrc = (rid < 32) ? nodes + ((size_t)b * 63 + rid) * 512
                                   : hF32 + ((size_t)rid * 32 + b) * 512;
    for (int u = tid; u < 512; u += 256) {
        out[b * 512 + u] = hsrc[u];
        float cv;
        if (rid < 32) {
            cv = cst[((size_t)rid * 32 + b) * 512 + u];
        } else {
            cv = cLoc[(size_t)(u >> 2) * NSLOTS * 32 * 4 + (size_t)rid * 128 + b * 4 + (u & 3)];
        }
        out[BH + b * 512 + u] = cv;
    }
}

extern "C" void kernel_launch(void* const* d_in, const int* in_sizes, int n_in,
                              void* d_out, int out_size, void* d_ws, size_t ws_size,
                              hipStream_t stream) {
    const float* inp    = (const float*)d_in[0];
    const int*   length = (const int*)d_in[1];
    const float* W_word = (const float*)d_in[2];
    const float* b_word = (const float*)d_in[3];
    const float* W_comp = (const float*)d_in[4];
    const float* b_comp = (const float*)d_in[5];
    const float* q      = (const float*)d_in[6];
    float* out = (float*)d_out;
    float* ws  = (float*)d_ws;

    _Float16*  Wth  = (_Float16*)(ws + OFF_WTH);
    _Float16*  Wtl  = (_Float16*)(ws + OFF_WTL);
    _Float16*  WpH  = (_Float16*)(ws + OFF_WPH);
    _Float16*  WpL  = (_Float16*)(ws + OFF_WPL);
    _Float16*  hHi  = (_Float16*)(ws + OFF_HHI);
    _Float16*  hLo  = (_Float16*)(ws + OFF_HLO);
    float*     hF32 = ws + OFF_HF32;
    float*     cst  = ws + OFF_CST;
    float*     cLoc = ws + OFF_CLOC;
    float*     lpart= ws + OFF_LPART;
    int*       selLog = (int*)(ws + OFF_SEL);
    u64*       elist  = (u64*)(ws + OFF_ELIST);
    int*       ireg   = (int*)(ws + OFF_IREG);

    init_kernel<<<4, 256, 0, stream>>>(ireg, elist, hHi, hLo);
    wsplit_kernel<<<dim3(NC5 / 32, 1024 / 32), 256, 0, stream>>>(W_comp, Wth, Wtl);
    wperm_kernel<<<128, 256, 0, stream>>>(Wth, Wtl, WpH, WpL);
    word_gemm64<<<dim3(16, 16), 256, 0, stream>>>(inp, W_word, b_word,
                                                  hHi, hLo, cst, out);
    tree_loop<<<NBLK, 256, 0, stream>>>(hHi, hLo, hF32, WpH, WpL, b_comp, q, length,
                                        cst, cLoc, lpart, elist, selLog, ireg);
    gather_kernel<<<NB, 256, 0, stream>>>(hF32, cst, cLoc, selLog, out);
}